// Round 1
// baseline (260.251 us; speedup 1.0000x reference)
//
#include <hip/hip_runtime.h>
#include <math.h>

#define BB 2
#define NN 512
#define DD 384
#define HSQK 192   // H*SQK
#define HPQ3 144   // H*PQ*3
#define NHP 48     // H*PQ
#define SCALEF 0.17677669529663687f  // 1/sqrt(16 + 4*4)

// ---------------- generic tiled GEMM: C = A @ W + bias ----------------
// A [M,K] row stride lda, W [K,Nc] row stride ldw, C row stride ldc.
// Optional batch via blockIdx.z with element strides sA/sW/sC.
// All of M, Nc, K must be multiples of 16 (true for every call here).
__global__ __launch_bounds__(256) void gemm_bias(
    const float* __restrict__ A, int lda, long sA,
    const float* __restrict__ W, int ldw, long sW,
    const float* __restrict__ bias,
    float* __restrict__ C, int ldc, long sC,
    int M, int Nc, int K) {
  __shared__ float As[16][17];
  __shared__ float Ws[16][17];
  int bz = blockIdx.z;
  A += (long)bz * sA; W += (long)bz * sW; C += (long)bz * sC;
  int tx = threadIdx.x, ty = threadIdx.y;
  int row = blockIdx.y * 16 + ty;
  int col = blockIdx.x * 16 + tx;
  float acc = 0.f;
  for (int k0 = 0; k0 < K; k0 += 16) {
    As[ty][tx] = A[(long)row * lda + k0 + tx];
    Ws[ty][tx] = W[(long)(k0 + ty) * ldw + col];
    __syncthreads();
#pragma unroll
    for (int kk = 0; kk < 16; ++kk)
      acc += As[ty][kk] * Ws[kk][tx];
    __syncthreads();
  }
  if (bias) acc += bias[col];
  C[(long)row * ldc + col] = acc;
}

// ---------------- per-(token,head,point) squared norm + inv norm ----------------
__global__ __launch_bounds__(256) void point_norms(
    const float* __restrict__ QP, float* __restrict__ N2v, float* __restrict__ INVv) {
  int idx = blockIdx.x * 256 + threadIdx.x;   // token*48 + hp
  if (idx >= BB * NN * NHP) return;
  int token = idx / NHP, hp = idx % NHP;
  const float* p = QP + (long)token * HPQ3 + hp * 3;
  float n2 = p[0] * p[0] + p[1] * p[1] + p[2] * p[2];
  N2v[idx] = n2;
  INVv[idx] = 1.0f / sqrtf(n2 + 1e-12f);
}

// ---------------- fused logits: (q.k + sum_hp(dist+cos)) * SCALE ----------------
#define QS_LD 196
#define QP_LD 148
#define NP_LD 49
__global__ __launch_bounds__(256) void logits_kernel(
    const float* __restrict__ QK, const float* __restrict__ QP,
    const float* __restrict__ N2v, const float* __restrict__ INVv,
    float* __restrict__ LOG) {
  __shared__ float Qs[16 * QS_LD];
  __shared__ float Ks[16 * QS_LD];
  __shared__ float Pi[16 * QP_LD];
  __shared__ float Pj[16 * QP_LD];
  __shared__ float n2i[16 * NP_LD], n2j[16 * NP_LD], ivi[16 * NP_LD], ivj[16 * NP_LD];
  int bb = blockIdx.z;
  int i0 = blockIdx.y * 16, j0 = blockIdx.x * 16;
  int tid = threadIdx.x;
  for (int idx = tid; idx < 16 * HSQK; idx += 256) {
    int r = idx / HSQK, c = idx % HSQK;
    Qs[r * QS_LD + c] = QK[((long)(bb * NN + i0 + r)) * 384 + c];
    Ks[r * QS_LD + c] = QK[((long)(bb * NN + j0 + r)) * 384 + 192 + c];
  }
  for (int idx = tid; idx < 16 * HPQ3; idx += 256) {
    int r = idx / HPQ3, c = idx % HPQ3;
    Pi[r * QP_LD + c] = QP[((long)(bb * NN + i0 + r)) * HPQ3 + c];
    Pj[r * QP_LD + c] = QP[((long)(bb * NN + j0 + r)) * HPQ3 + c];
  }
  for (int idx = tid; idx < 16 * NHP; idx += 256) {
    int r = idx / NHP, c = idx % NHP;
    n2i[r * NP_LD + c] = N2v[((long)(bb * NN + i0 + r)) * NHP + c];
    n2j[r * NP_LD + c] = N2v[((long)(bb * NN + j0 + r)) * NHP + c];
    ivi[r * NP_LD + c] = INVv[((long)(bb * NN + i0 + r)) * NHP + c];
    ivj[r * NP_LD + c] = INVv[((long)(bb * NN + j0 + r)) * NHP + c];
  }
  __syncthreads();
  int ti = tid >> 4, tj = tid & 15;
  float acc = 0.f;
  const float4* q4 = (const float4*)(Qs + ti * QS_LD);
  const float4* k4 = (const float4*)(Ks + tj * QS_LD);
#pragma unroll 8
  for (int k = 0; k < HSQK / 4; ++k) {
    float4 a = q4[k], b4 = k4[k];
    acc += a.x * b4.x + a.y * b4.y + a.z * b4.z + a.w * b4.w;
  }
  float pt = 0.f;
  const float* pi = Pi + ti * QP_LD;
  const float* pj = Pj + tj * QP_LD;
  const float* ni = n2i + ti * NP_LD;
  const float* nj = n2j + tj * NP_LD;
  const float* vi = ivi + ti * NP_LD;
  const float* vj = ivj + tj * NP_LD;
#pragma unroll 4
  for (int hp = 0; hp < NHP; ++hp) {
    float ax = pi[hp * 3], ay = pi[hp * 3 + 1], az = pi[hp * 3 + 2];
    float bx = pj[hp * 3], by = pj[hp * 3 + 1], bz = pj[hp * 3 + 2];
    float dot = ax * bx + ay * by + az * bz;
    float d2 = ni[hp] + nj[hp] - 2.f * dot;
    float dist = sqrtf(fmaxf(d2, 0.f) + 1e-12f);
    float cosv = dot * vi[hp] * vj[hp];
    pt += dist + cosv;
  }
  LOG[(long)bb * NN * NN + (long)(i0 + ti) * NN + (j0 + tj)] = (acc + pt) * SCALEF;
}

// ---------------- row softmax over N=512 ----------------
__global__ __launch_bounds__(256) void softmax_kernel(float* __restrict__ ATT) {
  int row = blockIdx.x;  // b*N + i
  float* p = ATT + (long)row * NN;
  int tid = threadIdx.x;
  float v0 = p[tid], v1 = p[tid + 256];
  __shared__ float red[256];
  red[tid] = fmaxf(v0, v1);
  __syncthreads();
  for (int s = 128; s > 0; s >>= 1) {
    if (tid < s) red[tid] = fmaxf(red[tid], red[tid + s]);
    __syncthreads();
  }
  float rowmax = red[0];
  __syncthreads();
  float e0 = expf(v0 - rowmax), e1 = expf(v1 - rowmax);
  red[tid] = e0 + e1;
  __syncthreads();
  for (int s = 128; s > 0; s >>= 1) {
    if (tid < s) red[tid] += red[tid + s];
    __syncthreads();
  }
  float inv = 1.0f / red[0];
  p[tid] = e0 * inv;
  p[tid + 256] = e1 * inv;
}

// ---------------- delta_xyz: out2 = xyz + mean_k PROJ[:,384+3k+c] ----------------
__global__ __launch_bounds__(128) void delta_kernel(
    const float* __restrict__ PROJ, const float* __restrict__ xyz,
    float* __restrict__ out2) {
  int token = blockIdx.x;  // b*N + n
  int t = threadIdx.x;     // 128 threads, one per 3-vector
  const float* pp = PROJ + (long)token * 768 + 384 + 3 * t;
  __shared__ float sx[128], sy[128], sz[128];
  sx[t] = pp[0]; sy[t] = pp[1]; sz[t] = pp[2];
  __syncthreads();
  for (int s = 64; s > 0; s >>= 1) {
    if (t < s) { sx[t] += sx[t + s]; sy[t] += sy[t + s]; sz[t] += sz[t + s]; }
    __syncthreads();
  }
  if (t == 0) {
    out2[(long)token * 3 + 0] = xyz[(long)token * 3 + 0] + sx[0] * (1.0f / 128.f);
    out2[(long)token * 3 + 1] = xyz[(long)token * 3 + 1] + sy[0] * (1.0f / 128.f);
    out2[(long)token * 3 + 2] = xyz[(long)token * 3 + 2] + sz[0] * (1.0f / 128.f);
  }
}

extern "C" void kernel_launch(void* const* d_in, const int* in_sizes, int n_in,
                              void* d_out, int out_size, void* d_ws, size_t ws_size,
                              hipStream_t stream) {
  const float* hidden = (const float*)d_in[0];
  const float* xyz   = (const float*)d_in[1];
  const float* W_qk  = (const float*)d_in[2];
  const float* b_qk  = (const float*)d_in[3];
  const float* W_vs  = (const float*)d_in[4];
  const float* b_vs  = (const float*)d_in[5];
  const float* W_so  = (const float*)d_in[6];
  const float* b_so  = (const float*)d_in[7];
  const float* W_pqk = (const float*)d_in[8];
  const float* b_pqk = (const float*)d_in[9];
  const float* W_pv  = (const float*)d_in[10];
  const float* b_pv  = (const float*)d_in[11];
  const float* W_po  = (const float*)d_in[12];
  const float* b_po  = (const float*)d_in[13];
  const float* W_fp  = (const float*)d_in[14];
  const float* b_fp  = (const float*)d_in[15];

  float* out_res = (float*)d_out;                 // [B,N,384]
  float* out_xyz = out_res + (long)BB * NN * DD;  // [B,N,3]

  float* ws   = (float*)d_ws;
  float* QK   = ws;                        // [1024,384]  q | k
  float* VVP  = QK  + 1024L * 384;         // [1024,480]  v_s | vp
  float* QP   = VVP + 1024L * 480;         // [1024,144]
  float* N2v  = QP  + 1024L * 144;         // [1024,48]
  float* INVv = N2v + 1024L * 48;          // [1024,48]
  float* ATT  = INVv+ 1024L * 48;          // [2,512,512]
  float* SRPR = ATT + 2L * 512 * 512;      // [1024,480]  scalar_res | point_res
  float* PROJ = SRPR+ 1024L * 480;         // [1024,768]  s_proj | p_proj

  dim3 blk(16, 16);
  // qk = hidden @ W_qk + b_qk  -> QK [1024,384]
  gemm_bias<<<dim3(24, 64, 1), blk, 0, stream>>>(hidden, DD, 0, W_qk, 384, 0, b_qk, QK, 384, 0, 1024, 384, DD);
  // v_s -> VVP[:,0:192]
  gemm_bias<<<dim3(12, 64, 1), blk, 0, stream>>>(hidden, DD, 0, W_vs, 192, 0, b_vs, VVP, 480, 0, 1024, 192, DD);
  // vp -> VVP[:,192:480]
  gemm_bias<<<dim3(18, 64, 1), blk, 0, stream>>>(hidden, DD, 0, W_pv, 288, 0, b_pv, VVP + 192, 480, 0, 1024, 288, DD);
  // qp -> QP [1024,144]
  gemm_bias<<<dim3(9, 64, 1), blk, 0, stream>>>(hidden, DD, 0, W_pqk, 144, 0, b_pqk, QP, 144, 0, 1024, 144, DD);

  point_norms<<<(1024 * 48 + 255) / 256, 256, 0, stream>>>(QP, N2v, INVv);

  logits_kernel<<<dim3(32, 32, 2), 256, 0, stream>>>(QK, QP, N2v, INVv, ATT);
  softmax_kernel<<<1024, 256, 0, stream>>>(ATT);

  // [scalar_result | point_result] = attn @ VVP   (per batch)
  gemm_bias<<<dim3(30, 32, 2), blk, 0, stream>>>(ATT, 512, 512L * 512, VVP, 480, 512L * 480, nullptr, SRPR, 480, 512L * 480, 512, 480, 512);

  // scalar_result @ W_so + b_so -> PROJ[:,0:384]
  gemm_bias<<<dim3(24, 64, 1), blk, 0, stream>>>(SRPR, 480, 0, W_so, 384, 0, b_so, PROJ, 768, 0, 1024, 384, 192);
  // point_result @ W_po + b_po -> PROJ[:,384:768]
  gemm_bias<<<dim3(24, 64, 1), blk, 0, stream>>>(SRPR + 192, 480, 0, W_po, 384, 0, b_po, PROJ + 384, 768, 0, 1024, 384, 288);
  // result = PROJ @ W_fp + b_fp
  gemm_bias<<<dim3(24, 64, 1), blk, 0, stream>>>(PROJ, 768, 0, W_fp, 384, 0, b_fp, out_res, 384, 0, 1024, 384, 768);

  delta_kernel<<<1024, 128, 0, stream>>>(PROJ, xyz, out_xyz);
}